// Round 2
// baseline (1023.068 us; speedup 1.0000x reference)
//
#include <hip/hip_runtime.h>
#include <cstdint>
#include <cstddef>

#define NP    8500   // priors
#define BS    32     // batch
#define NGT   128    // gt boxes
#define NCLS  80     // classes
#define TOPKK 10

typedef unsigned long long u64;
typedef unsigned int u32;

static __device__ __forceinline__ float iou_fn(const float4 a, const float4 b) {
  float area_a = (a.z - a.x) * (a.w - a.y);
  float area_b = (b.z - b.x) * (b.w - b.y);
  float tlx = fmaxf(a.x, b.x), tly = fmaxf(a.y, b.y);
  float brx = fminf(a.z, b.z), bry = fminf(a.w, b.w);
  float ww = fmaxf(brx - tlx, 0.f), hh = fmaxf(bry - tly, 0.f);
  float inter = ww * hh;
  return inter / (area_a + area_b - inter + 1e-16f);
}

static __device__ __forceinline__ float clampp(float p) {
  return fminf(fmaxf(p, 1e-7f), 1.0f - 1e-7f);
}

static __device__ __forceinline__ float cost_fn(const float4 db, const float4 gb,
                                                float negsum, float praw,
                                                bool inb, bool vn) {
  float iou  = iou_fn(db, gb);
  float iouc = -logf(iou + 1e-8f);
  float p    = clampp(praw);
  float negl = -log1pf(-p);
  float posl = -logf(p);
  float clsc = (negsum - negl) + posl;
  float c = clsc + 3.0f * iouc;
  c += inb ? 0.f : 1e5f;
  c += vn  ? 0.f : 1e8f;
  return c;
}

static __device__ __forceinline__ u64 shflxor_u64(u64 v, int mask) {
  int lo = __shfl_xor((int)(u32)(v & 0xffffffffull), mask, 64);
  int hi = __shfl_xor((int)(u32)(v >> 32), mask, 64);
  return ((u64)(u32)hi << 32) | (u32)lo;
}

// monotonic float->u32 (robust even if cost were negative)
static __device__ __forceinline__ u32 f2u_mono(float f) {
  u32 b = __float_as_uint(f);
  return b ^ ((b & 0x80000000u) ? 0xffffffffu : 0x80000000u);
}

// ---------------- kernel 1: per-prior masks + neg_sum ----------------
__global__ __launch_bounds__(256) void k_prep(
    const float* __restrict__ priors, const float* __restrict__ gtb,
    const float* __restrict__ clsp,
    float* __restrict__ negsum, unsigned char* __restrict__ valid,
    u64* __restrict__ inboth)
{
  __shared__ float4 sg[NGT];
  const int b = blockIdx.y;
  const int tid = threadIdx.x;
  if (tid < NGT) sg[tid] = reinterpret_cast<const float4*>(gtb + (size_t)b * NGT * 4)[tid];
  __syncthreads();
  const int n = blockIdx.x * 256 + tid;
  if (n >= NP) return;
  const float4 pr = reinterpret_cast<const float4*>(priors)[n];
  const float cx = pr.x, cy = pr.y, sw = pr.z, sh = pr.w;
  u64 m0 = 0, m1 = 0;
  bool anyv = false;
  const float CR = 2.5f;
  for (int g = 0; g < NGT; ++g) {
    float4 gb = sg[g];
    float ib = fminf(fminf(cx - gb.x, cy - gb.y), fminf(gb.z - cx, gb.w - cy));
    bool in_box = ib > 0.f;
    float gcx = (gb.x + gb.z) * 0.5f, gcy = (gb.y + gb.w) * 0.5f;
    float ic = fminf(fminf(cx - (gcx - CR * sw), cy - (gcy - CR * sh)),
                     fminf(gcx + CR * sw - cx, gcy + CR * sh - cy));
    bool in_ctr = ic > 0.f;
    anyv |= (in_box | in_ctr);
    if (in_box && in_ctr) {
      if (g < 64) m0 |= 1ull << g; else m1 |= 1ull << (g - 64);
    }
  }
  const size_t idx = (size_t)b * NP + n;
  valid[idx] = anyv ? 1 : 0;
  inboth[idx * 2] = m0;
  inboth[idx * 2 + 1] = m1;
  const float4* row4 = reinterpret_cast<const float4*>(clsp + idx * NCLS);
  float s = 0.f;
  #pragma unroll 5
  for (int i = 0; i < NCLS / 4; ++i) {
    float4 p4 = row4[i];
    float ps[4] = {p4.x, p4.y, p4.z, p4.w};
    #pragma unroll
    for (int j = 0; j < 4; ++j) {
      float p = clampp(ps[j]);
      s += -log1pf(-p);
    }
  }
  negsum[idx] = s;
}

// ---------------- kernel 2: per-(image,gt) dyn_k + top-k selection ----------------
__global__ __launch_bounds__(256) void k_assign(
    const float* __restrict__ dec, const float* __restrict__ gtb,
    const int* __restrict__ gtl, const float* __restrict__ clsp,
    const float* __restrict__ negsum, const unsigned char* __restrict__ valid,
    const u64* __restrict__ inboth, u64* __restrict__ match)
{
  const int wid = (blockIdx.x * 256 + threadIdx.x) >> 6;
  const int lane = threadIdx.x & 63;
  if (wid >= BS * NGT) return;
  const int b = wid >> 7;      // /NGT
  const int g = wid & 127;     // %NGT
  const float4 gb = reinterpret_cast<const float4*>(gtb)[b * NGT + g];
  const int l = gtl[b * NGT + g];
  const float4* decb = reinterpret_cast<const float4*>(dec) + (size_t)b * NP;
  const float* negb = negsum + (size_t)b * NP;
  const unsigned char* valb = valid + (size_t)b * NP;
  const u64* inbb = inboth + (size_t)b * NP * 2;
  const float* clspb = clsp + (size_t)b * NP * NCLS;

  // ---- phase 1: top-10 of valid-masked ious -> dyn_k ----
  float t[TOPKK];
  #pragma unroll
  for (int i = 0; i < TOPKK; ++i) t[i] = 0.f;
  for (int n = lane; n < NP; n += 64) {
    float iou = iou_fn(decb[n], gb);
    float v = valb[n] ? iou : 0.f;
    if (v > t[0]) {
      t[0] = v;
      #pragma unroll
      for (int i = 0; i < TOPKK - 1; ++i) {
        if (t[i] > t[i + 1]) { float tmp = t[i]; t[i] = t[i + 1]; t[i + 1] = tmp; }
        else break;
      }
    }
  }
  float sum = 0.f;
  int ptr = TOPKK - 1;
  for (int r = 0; r < TOPKK; ++r) {
    float cand = (ptr >= 0) ? t[ptr] : -1.f;
    float m = cand;
    #pragma unroll
    for (int off = 32; off; off >>= 1) m = fmaxf(m, __shfl_xor(m, off, 64));
    u64 ball = __ballot(cand == m);
    int win = __ffsll(ball) - 1;
    if (lane == win) ptr--;
    sum += fmaxf(m, 0.f);
  }
  int dynk = (int)sum;
  if (dynk < 1) dynk = 1;
  if (dynk > TOPKK) dynk = TOPKK;

  // ---- phase 2: dyn_k smallest (cost, index) ----
  u64 k[TOPKK];
  #pragma unroll
  for (int i = 0; i < TOPKK; ++i) k[i] = ~0ull;
  for (int n = lane; n < NP; n += 64) {
    float4 db = decb[n];
    bool inb = ((inbb[2 * (size_t)n + (g >> 6)] >> (g & 63)) & 1ull) != 0;
    float c = cost_fn(db, gb, negb[n], clspb[(size_t)n * NCLS + l], inb, valb[n] != 0);
    u64 key = ((u64)f2u_mono(c) << 32) | (u32)n;
    if (key < k[TOPKK - 1]) {
      k[TOPKK - 1] = key;
      #pragma unroll
      for (int i = TOPKK - 1; i > 0; --i) {
        if (k[i] < k[i - 1]) { u64 tmp = k[i]; k[i] = k[i - 1]; k[i - 1] = tmp; }
        else break;
      }
    }
  }
  int p2 = 0;
  for (int r = 0; r < dynk; ++r) {
    u64 cand = (p2 < TOPKK) ? k[p2] : ~0ull;
    u64 m = cand;
    #pragma unroll
    for (int off = 32; off; off >>= 1) {
      u64 o = shflxor_u64(m, off);
      if (o < m) m = o;
    }
    u64 ball = __ballot(cand == m);
    int win = __ffsll(ball) - 1;
    if (lane == win) {
      p2++;
      u32 nn = (u32)(m & 0xffffffffu);
      atomicOr(&match[((size_t)b * NP + nn) * 2 + (g >> 6)], 1ull << (g & 63));
    }
  }
}

// ---------------- kernel 3: resolve matches, tscore/mgt, npos/ns partials ----------------
__global__ __launch_bounds__(256) void k_post(
    const float* __restrict__ dec, const float* __restrict__ gtb,
    const int* __restrict__ gtl, const float* __restrict__ clsp,
    const float* __restrict__ negsum, const unsigned char* __restrict__ valid,
    const u64* __restrict__ inboth, const u64* __restrict__ match,
    float* __restrict__ tscore, int* __restrict__ mgt,
    float* __restrict__ p_np, float* __restrict__ p_ns)
{
  const int b = blockIdx.y;
  const int tid = threadIdx.x;
  const int n = blockIdx.x * 256 + tid;
  float ts = 0.f, fgf = 0.f;
  if (n < NP) {
    const size_t idx = (size_t)b * NP + n;
    u64 m0 = match[idx * 2], m1 = match[idx * 2 + 1];
    int pop = __popcll(m0) + __popcll(m1);
    int mg = 0;
    if (pop > 0) {
      fgf = 1.f;
      float4 db = reinterpret_cast<const float4*>(dec)[idx];
      int g;
      if (pop == 1) {
        g = m0 ? (__ffsll(m0) - 1) : (64 + __ffsll(m1) - 1);
      } else {
        float nsv = negsum[idx];
        bool vn = valid[idx] != 0;
        u64 ib0 = inboth[idx * 2], ib1 = inboth[idx * 2 + 1];
        float bc = 3.4e38f; int bg_ = 0;
        for (int gg = 0; gg < NGT; ++gg) {
          float4 gbv = reinterpret_cast<const float4*>(gtb)[b * NGT + gg];
          int l = gtl[b * NGT + gg];
          bool inb = (((gg < 64) ? (ib0 >> gg) : (ib1 >> (gg - 64))) & 1ull) != 0;
          float c = cost_fn(db, gbv, nsv, clsp[idx * NCLS + l], inb, vn);
          if (c < bc) { bc = c; bg_ = gg; }
        }
        g = bg_;
      }
      mg = g;
      ts = iou_fn(db, reinterpret_cast<const float4*>(gtb)[b * NGT + g]);
    }
    tscore[idx] = ts;
    mgt[idx] = mg;
  }
  __shared__ float red[256];
  red[tid] = fgf; __syncthreads();
  for (int s = 128; s > 0; s >>= 1) { if (tid < s) red[tid] += red[tid + s]; __syncthreads(); }
  float npb = red[0]; __syncthreads();
  red[tid] = ts; __syncthreads();
  for (int s = 128; s > 0; s >>= 1) { if (tid < s) red[tid] += red[tid + s]; __syncthreads(); }
  if (tid == 0) {
    int blk = blockIdx.y * gridDim.x + blockIdx.x;
    p_np[blk] = npb;
    p_ns[blk] = red[0];
  }
}

// ---------------- kernel 4: VFL + GIoU + DFL partials ----------------
__global__ __launch_bounds__(256) void k_loss(
    const float* __restrict__ priors, const float* __restrict__ dec,
    const float* __restrict__ clsp, const float* __restrict__ regp,
    const float* __restrict__ gtb, const int* __restrict__ gtl,
    const float* __restrict__ tscore, const int* __restrict__ mgt,
    float* __restrict__ p_vfl, float* __restrict__ p_gi, float* __restrict__ p_df)
{
  const int b = blockIdx.y;
  const int tid = threadIdx.x;
  const int n = blockIdx.x * 256 + tid;
  float vfl = 0.f, gi = 0.f, df = 0.f;
  if (n < NP) {
    const size_t idx = (size_t)b * NP + n;
    const float ts = tscore[idx];
    const int mg = mgt[idx];
    const float* row = clsp + idx * NCLS;
    const float4* row4 = reinterpret_cast<const float4*>(row);
    // background part for all classes (single log each)
    #pragma unroll 5
    for (int i = 0; i < NCLS / 4; ++i) {
      float4 p4 = row4[i];
      float ps[4] = {p4.x, p4.y, p4.z, p4.w};
      #pragma unroll
      for (int j = 0; j < 4; ++j) {
        float p = clampp(ps[j]);
        vfl += (-log1pf(-p)) * (0.75f * p * p);
      }
    }
    if (ts > 0.f) {
      const int lbl = gtl[b * NGT + mg];
      // replace the lbl class's background term with the foreground term
      float p = clampp(row[lbl]);
      float l1 = log1pf(-p);
      vfl -= (-l1) * (0.75f * p * p);
      vfl += (-(ts * logf(p) + (1.f - ts) * l1)) * ts;

      const float4 ab = reinterpret_cast<const float4*>(gtb)[b * NGT + mg];
      const float4 db = reinterpret_cast<const float4*>(dec)[idx];
      // GIoU
      {
        float tlx = fmaxf(db.x, ab.x), tly = fmaxf(db.y, ab.y);
        float brx = fminf(db.z, ab.z), bry = fminf(db.w, ab.w);
        float iw = fmaxf(brx - tlx, 0.f), ih = fmaxf(bry - tly, 0.f);
        float inter = iw * ih;
        float ap = fmaxf(db.z - db.x, 0.f) * fmaxf(db.w - db.y, 0.f);
        float at = fmaxf(ab.z - ab.x, 0.f) * fmaxf(ab.w - ab.y, 0.f);
        float uni = ap + at - inter;
        float iou = inter / (uni + 1e-16f);
        float ctlx = fminf(db.x, ab.x), ctly = fminf(db.y, ab.y);
        float cbrx = fmaxf(db.z, ab.z), cbry = fmaxf(db.w, ab.w);
        float cw = fmaxf(cbrx - ctlx, 0.f), ch = fmaxf(cbry - ctly, 0.f);
        float ac = cw * ch;
        float gl = 1.f - (iou - (ac - uni) / (ac + 1e-16f));
        gi = gl * ts;
      }
      // DFL
      {
        const float4 pr = reinterpret_cast<const float4*>(priors)[n];
        const float s = pr.z;
        float dv[4] = {(pr.x - ab.x) / s, (pr.y - ab.y) / s,
                       (ab.z - pr.x) / s, (ab.w - pr.y) / s};
        const float* rrow = regp + idx * 32;
        float ce_sum = 0.f;
        #pragma unroll
        for (int side = 0; side < 4; ++side) {
          float tv = fminf(fmaxf(dv[side], 0.f), 6.9f);
          int tl_ = (int)tv;
          int tr_ = tl_ + 1; if (tr_ > 7) tr_ = 7;
          float wl = (float)(tl_ + 1) - tv;
          float wr = tv - (float)tl_;
          const float* lg = rrow + side * 8;
          float mx = lg[0];
          #pragma unroll
          for (int i = 1; i < 8; ++i) mx = fmaxf(mx, lg[i]);
          float se = 0.f;
          #pragma unroll
          for (int i = 0; i < 8; ++i) se += expf(lg[i] - mx);
          float lse = logf(se);
          float lp_tl = lg[tl_] - mx - lse;
          float lp_tr = lg[tr_] - mx - lse;
          ce_sum += -(lp_tl * wl + lp_tr * wr);
        }
        df = ce_sum * ts;
      }
    }
  }
  __shared__ float red[256];
  red[tid] = vfl; __syncthreads();
  for (int s = 128; s > 0; s >>= 1) { if (tid < s) red[tid] += red[tid + s]; __syncthreads(); }
  float vflb = red[0]; __syncthreads();
  red[tid] = gi; __syncthreads();
  for (int s = 128; s > 0; s >>= 1) { if (tid < s) red[tid] += red[tid + s]; __syncthreads(); }
  float gib = red[0]; __syncthreads();
  red[tid] = df; __syncthreads();
  for (int s = 128; s > 0; s >>= 1) { if (tid < s) red[tid] += red[tid + s]; __syncthreads(); }
  if (tid == 0) {
    int blk = blockIdx.y * gridDim.x + blockIdx.x;
    p_vfl[blk] = vflb;
    p_gi[blk] = gib;
    p_df[blk] = red[0];
  }
}

// ---------------- kernel 5: final reduction + combine ----------------
__global__ __launch_bounds__(256) void k_final(
    const float* __restrict__ p_vfl, const float* __restrict__ p_gi,
    const float* __restrict__ p_df, const float* __restrict__ p_np,
    const float* __restrict__ p_ns, float* __restrict__ out, int nb)
{
  __shared__ double red[256];
  const float* arrs[5] = {p_vfl, p_gi, p_df, p_np, p_ns};
  double sums[5];
  for (int a = 0; a < 5; ++a) {
    double s = 0.0;
    for (int i = threadIdx.x; i < nb; i += 256) s += (double)arrs[a][i];
    red[threadIdx.x] = s; __syncthreads();
    for (int st = 128; st > 0; st >>= 1) {
      if (threadIdx.x < st) red[threadIdx.x] += red[threadIdx.x + st];
      __syncthreads();
    }
    sums[a] = red[0]; __syncthreads();
  }
  if (threadIdx.x == 0) {
    double npos = sums[3] > 1.0 ? sums[3] : 1.0;
    double ns = sums[4] > 1.0 ? sums[4] : 1.0;
    out[0] = (float)(sums[0] / npos + 2.0 * sums[1] / ns + 0.25 * sums[2] / ns);
  }
}

extern "C" void kernel_launch(void* const* d_in, const int* in_sizes, int n_in,
                              void* d_out, int out_size, void* d_ws, size_t ws_size,
                              hipStream_t stream) {
  const float* priors = (const float*)d_in[0];
  const float* dec    = (const float*)d_in[1];
  const float* clsp   = (const float*)d_in[2];
  const float* regp   = (const float*)d_in[3];
  const float* gtb    = (const float*)d_in[4];
  const int*   gtl    = (const int*)d_in[5];
  float* out = (float*)d_out;

  char* w = (char*)d_ws;
  size_t off = 0;
  auto take = [&](size_t bytes) -> char* {
    char* p = w + off;
    off += (bytes + 255) & ~(size_t)255;
    return p;
  };
  float* negsum        = (float*)take((size_t)BS * NP * 4);
  unsigned char* valid = (unsigned char*)take((size_t)BS * NP);
  u64* inboth          = (u64*)take((size_t)BS * NP * 16);
  u64* match           = (u64*)take((size_t)BS * NP * 16);
  float* tscore        = (float*)take((size_t)BS * NP * 4);
  int* mgt             = (int*)take((size_t)BS * NP * 4);
  const int NBX = (NP + 255) / 256;        // 34
  const int NBLK = NBX * BS;               // 1088
  float* p_vfl = (float*)take((size_t)NBLK * 4);
  float* p_gi  = (float*)take((size_t)NBLK * 4);
  float* p_df  = (float*)take((size_t)NBLK * 4);
  float* p_np  = (float*)take((size_t)NBLK * 4);
  float* p_ns  = (float*)take((size_t)NBLK * 4);

  hipMemsetAsync(match, 0, (size_t)BS * NP * 16, stream);

  dim3 gridA(NBX, BS);
  k_prep<<<gridA, 256, 0, stream>>>(priors, gtb, clsp, negsum, valid, inboth);
  k_assign<<<dim3(BS * NGT / 4), 256, 0, stream>>>(dec, gtb, gtl, clsp, negsum,
                                                   valid, inboth, match);
  k_post<<<gridA, 256, 0, stream>>>(dec, gtb, gtl, clsp, negsum, valid, inboth,
                                    match, tscore, mgt, p_np, p_ns);
  k_loss<<<gridA, 256, 0, stream>>>(priors, dec, clsp, regp, gtb, gtl,
                                    tscore, mgt, p_vfl, p_gi, p_df);
  k_final<<<1, 256, 0, stream>>>(p_vfl, p_gi, p_df, p_np, p_ns, out, NBLK);
}

// Round 3
// 632.643 us; speedup vs baseline: 1.6171x; 1.6171x over previous
//
#include <hip/hip_runtime.h>
#include <cstdint>
#include <cstddef>

#define NP    8500   // priors
#define BS    32     // batch
#define NGT   128    // gt boxes
#define NCLS  80     // classes
#define TOPKK 10

typedef unsigned long long u64;
typedef unsigned int u32;

static __device__ __forceinline__ float iou_fn(const float4 a, const float4 b) {
  float area_a = (a.z - a.x) * (a.w - a.y);
  float area_b = (b.z - b.x) * (b.w - b.y);
  float tlx = fmaxf(a.x, b.x), tly = fmaxf(a.y, b.y);
  float brx = fminf(a.z, b.z), bry = fminf(a.w, b.w);
  float ww = fmaxf(brx - tlx, 0.f), hh = fmaxf(bry - tly, 0.f);
  float inter = ww * hh;
  return inter / (area_a + area_b - inter + 1e-16f);
}

static __device__ __forceinline__ float clampp(float p) {
  return fminf(fmaxf(p, 1e-7f), 1.0f - 1e-7f);
}

// log((1-p)/p) = log1p(-p) - log(p)  (one hw log instead of two libm calls)
static __device__ __forceinline__ float wlog(float p) {
  return __logf((1.0f - p) / p);
}

static __device__ __forceinline__ u64 shflxor_u64(u64 v, int mask) {
  int lo = __shfl_xor((int)(u32)(v & 0xffffffffull), mask, 64);
  int hi = __shfl_xor((int)(u32)(v >> 32), mask, 64);
  return ((u64)(u32)hi << 32) | (u32)lo;
}

static __device__ __forceinline__ u32 f2u_mono(float f) {
  u32 b = __float_as_uint(f);
  return b ^ ((b & 0x80000000u) ? 0xffffffffu : 0x80000000u);
}

// ---------------- kernel 1: masks + negsum (+ transposed cls-cost rows) ----------------
template<bool TR>
__global__ __launch_bounds__(256) void k_prep(
    const float* __restrict__ priors, const float* __restrict__ gtb,
    const float* __restrict__ clsp,
    float* __restrict__ negsum, unsigned char* __restrict__ valid,
    u64* __restrict__ inboth, float* __restrict__ ccostT)
{
  __shared__ float4 sg[NGT];
  const int b = blockIdx.y;
  const int tid = threadIdx.x;
  if (tid < NGT) sg[tid] = reinterpret_cast<const float4*>(gtb + (size_t)b * NGT * 4)[tid];
  __syncthreads();
  const int n = blockIdx.x * 256 + tid;
  if (n >= NP) return;
  const float4 pr = reinterpret_cast<const float4*>(priors)[n];
  const float cx = pr.x, cy = pr.y, sw = pr.z, sh = pr.w;
  u64 m0 = 0, m1 = 0;
  bool anyv = false;
  const float CR = 2.5f;
  for (int g = 0; g < NGT; ++g) {
    float4 gb = sg[g];
    float ib = fminf(fminf(cx - gb.x, cy - gb.y), fminf(gb.z - cx, gb.w - cy));
    bool in_box = ib > 0.f;
    float gcx = (gb.x + gb.z) * 0.5f, gcy = (gb.y + gb.w) * 0.5f;
    float ic = fminf(fminf(cx - (gcx - CR * sw), cy - (gcy - CR * sh)),
                     fminf(gcx + CR * sw - cx, gcy + CR * sh - cy));
    bool in_ctr = ic > 0.f;
    anyv |= (in_box | in_ctr);
    if (in_box && in_ctr) {
      if (g < 64) m0 |= 1ull << g; else m1 |= 1ull << (g - 64);
    }
  }
  const size_t idx = (size_t)b * NP + n;
  valid[idx] = anyv ? 1 : 0;
  inboth[idx * 2] = m0;
  inboth[idx * 2 + 1] = m1;

  // negsum = sum_c -log1p(-p) = -sum log(1-p); chunk 4 products per hw log
  const float4* row4 = reinterpret_cast<const float4*>(clsp + idx * NCLS);
  float s = 0.f;
  #pragma unroll 5
  for (int i = 0; i < NCLS / 4; ++i) {
    float4 p4 = row4[i];
    float q0 = 1.f - clampp(p4.x), q1 = 1.f - clampp(p4.y);
    float q2 = 1.f - clampp(p4.z), q3 = 1.f - clampp(p4.w);
    s -= __logf((q0 * q1) * (q2 * q3));
  }
  negsum[idx] = s;

  if (TR) {
    // ccostT[b][c][n] = negsum + log((1-p)/p)  (k_assign's per-class base cost)
    #pragma unroll 5
    for (int i = 0; i < NCLS / 4; ++i) {
      float4 p4 = row4[i];   // L1 hit
      float w0 = wlog(clampp(p4.x)), w1 = wlog(clampp(p4.y));
      float w2 = wlog(clampp(p4.z)), w3 = wlog(clampp(p4.w));
      const size_t base = ((size_t)b * NCLS + i * 4) * NP + n;
      ccostT[base]          = s + w0;
      ccostT[base + NP]     = s + w1;
      ccostT[base + 2 * NP] = s + w2;
      ccostT[base + 3 * NP] = s + w3;
    }
  }
}

// ---------------- kernel 2: fused single-scan dyn_k + top-k selection ----------------
template<bool TR>
__global__ __launch_bounds__(256) void k_assign(
    const float* __restrict__ dec, const float* __restrict__ gtb,
    const int* __restrict__ gtl, const float* __restrict__ clsp,
    const float* __restrict__ negsum, const unsigned char* __restrict__ valid,
    const u64* __restrict__ inboth, const float* __restrict__ ccostT,
    u64* __restrict__ match)
{
  // XCD-aware remap: 1024 blocks, 8 XCDs -> each XCD owns 4 consecutive images
  const int bid = (int)((blockIdx.x & 7) * (gridDim.x >> 3) + (blockIdx.x >> 3));
  const int wid = (bid * 256 + (int)threadIdx.x) >> 6;
  const int lane = threadIdx.x & 63;
  const int b = wid >> 7;      // /NGT
  const int g = wid & 127;     // %NGT
  const float4 gb = reinterpret_cast<const float4*>(gtb)[b * NGT + g];
  const int l = gtl[b * NGT + g];
  const float4* decb = reinterpret_cast<const float4*>(dec) + (size_t)b * NP;
  const unsigned char* valb = valid + (size_t)b * NP;
  const u64* inbb = inboth + (size_t)b * NP * 2;
  const float* ccrow = TR ? (ccostT + ((size_t)b * NCLS + l) * NP) : nullptr;
  const float* negb = negsum + (size_t)b * NP;
  const float* clspb = clsp + (size_t)b * NP * NCLS;

  float t[TOPKK];          // ascending top-10 masked ious
  u64 k[TOPKK];            // ascending smallest-10 (cost,idx) keys
  #pragma unroll
  for (int i = 0; i < TOPKK; ++i) { t[i] = 0.f; k[i] = ~0ull; }

  for (int n = lane; n < NP; n += 64) {
    const float4 db = decb[n];
    const bool vn = valb[n] != 0;
    const float iou = iou_fn(db, gb);
    const float v = vn ? iou : 0.f;
    if (v > t[0]) {
      t[0] = v;
      #pragma unroll
      for (int i = 0; i < TOPKK - 1; ++i) {
        if (t[i] > t[i + 1]) { float tmp = t[i]; t[i] = t[i + 1]; t[i + 1] = tmp; }
        else break;
      }
    }
    float base;
    if (TR) base = ccrow[n];
    else {
      float p = clampp(clspb[(size_t)n * NCLS + l]);
      base = negb[n] + wlog(p);
    }
    const bool inb = ((inbb[2 * (size_t)n + (g >> 6)] >> (g & 63)) & 1ull) != 0;
    float c = fmaf(-3.f, __logf(iou + 1e-8f), base);
    c += inb ? 0.f : 1e5f;
    c += vn ? 0.f : 1e8f;
    const u64 key = ((u64)f2u_mono(c) << 32) | (u32)n;
    if (key < k[TOPKK - 1]) {
      k[TOPKK - 1] = key;
      #pragma unroll
      for (int i = TOPKK - 1; i > 0; --i) {
        if (k[i] < k[i - 1]) { u64 tmp = k[i]; k[i] = k[i - 1]; k[i - 1] = tmp; }
        else break;
      }
    }
  }

  // ---- merge ious across lanes -> dyn_k ----
  float sum = 0.f;
  int ptr = TOPKK - 1;
  for (int r = 0; r < TOPKK; ++r) {
    float cand = (ptr >= 0) ? t[ptr] : -1.f;
    float m = cand;
    #pragma unroll
    for (int off = 32; off; off >>= 1) m = fmaxf(m, __shfl_xor(m, off, 64));
    u64 ball = __ballot(cand == m);
    int win = __ffsll(ball) - 1;
    if (lane == win) ptr--;
    sum += fmaxf(m, 0.f);
  }
  int dynk = (int)sum;
  if (dynk < 1) dynk = 1;
  if (dynk > TOPKK) dynk = TOPKK;

  // ---- extract dyn_k smallest keys ----
  int p2 = 0;
  for (int r = 0; r < dynk; ++r) {
    u64 cand = (p2 < TOPKK) ? k[p2] : ~0ull;
    u64 m = cand;
    #pragma unroll
    for (int off = 32; off; off >>= 1) {
      u64 o = shflxor_u64(m, off);
      if (o < m) m = o;
    }
    u64 ball = __ballot(cand == m);
    int win = __ffsll(ball) - 1;
    if (lane == win) {
      p2++;
      u32 nn = (u32)(m & 0xffffffffu);
      atomicOr(&match[((size_t)b * NP + nn) * 2 + (g >> 6)], 1ull << (g & 63));
    }
  }
}

// ---------------- kernel 3: resolve matches ----------------
template<bool TR>
__global__ __launch_bounds__(256) void k_post(
    const float* __restrict__ dec, const float* __restrict__ gtb,
    const int* __restrict__ gtl, const float* __restrict__ clsp,
    const float* __restrict__ negsum, const unsigned char* __restrict__ valid,
    const u64* __restrict__ inboth, const float* __restrict__ ccostT,
    const u64* __restrict__ match,
    float* __restrict__ tscore, int* __restrict__ mgt,
    float* __restrict__ p_np, float* __restrict__ p_ns)
{
  const int b = blockIdx.y;
  const int tid = threadIdx.x;
  const int n = blockIdx.x * 256 + tid;
  float ts = 0.f, fgf = 0.f;
  if (n < NP) {
    const size_t idx = (size_t)b * NP + n;
    u64 m0 = match[idx * 2], m1 = match[idx * 2 + 1];
    int pop = __popcll(m0) + __popcll(m1);
    int mg = 0;
    if (pop > 0) {
      fgf = 1.f;
      float4 db = reinterpret_cast<const float4*>(dec)[idx];
      int g;
      if (pop == 1) {
        g = m0 ? (__ffsll(m0) - 1) : (64 + __ffsll(m1) - 1);
      } else {
        bool vn = valid[idx] != 0;
        u64 ib0 = inboth[idx * 2], ib1 = inboth[idx * 2 + 1];
        float nsv = negsum[idx];
        float bc = 3.4e38f; int bg_ = 0;
        for (int gg = 0; gg < NGT; ++gg) {
          float4 gbv = reinterpret_cast<const float4*>(gtb)[b * NGT + gg];
          int lg_ = gtl[b * NGT + gg];
          float base;
          if (TR) base = ccostT[((size_t)b * NCLS + lg_) * NP + n];
          else    base = nsv + wlog(clampp(clsp[idx * NCLS + lg_]));
          bool inb = (((gg < 64) ? (ib0 >> gg) : (ib1 >> (gg - 64))) & 1ull) != 0;
          float iou = iou_fn(db, gbv);
          float c = fmaf(-3.f, __logf(iou + 1e-8f), base);
          c += inb ? 0.f : 1e5f;
          c += vn ? 0.f : 1e8f;
          if (c < bc) { bc = c; bg_ = gg; }
        }
        g = bg_;
      }
      mg = g;
      ts = iou_fn(db, reinterpret_cast<const float4*>(gtb)[b * NGT + g]);
    }
    tscore[idx] = ts;
    mgt[idx] = mg;
  }
  __shared__ float red[256];
  red[tid] = fgf; __syncthreads();
  for (int s = 128; s > 0; s >>= 1) { if (tid < s) red[tid] += red[tid + s]; __syncthreads(); }
  float npb = red[0]; __syncthreads();
  red[tid] = ts; __syncthreads();
  for (int s = 128; s > 0; s >>= 1) { if (tid < s) red[tid] += red[tid + s]; __syncthreads(); }
  if (tid == 0) {
    int blk = blockIdx.y * gridDim.x + blockIdx.x;
    p_np[blk] = npb;
    p_ns[blk] = red[0];
  }
}

// ---------------- kernel 4: VFL + GIoU + DFL partials ----------------
__global__ __launch_bounds__(256) void k_loss(
    const float* __restrict__ priors, const float* __restrict__ dec,
    const float* __restrict__ clsp, const float* __restrict__ regp,
    const float* __restrict__ gtb, const int* __restrict__ gtl,
    const float* __restrict__ tscore, const int* __restrict__ mgt,
    float* __restrict__ p_vfl, float* __restrict__ p_gi, float* __restrict__ p_df)
{
  const int b = blockIdx.y;
  const int tid = threadIdx.x;
  const int n = blockIdx.x * 256 + tid;
  float vfl = 0.f, gi = 0.f, df = 0.f;
  if (n < NP) {
    const size_t idx = (size_t)b * NP + n;
    const float ts = tscore[idx];
    const int mg = mgt[idx];
    const float* row = clsp + idx * NCLS;
    const float4* row4 = reinterpret_cast<const float4*>(row);
    #pragma unroll 5
    for (int i = 0; i < NCLS / 4; ++i) {
      float4 p4 = row4[i];
      float ps[4] = {p4.x, p4.y, p4.z, p4.w};
      #pragma unroll
      for (int j = 0; j < 4; ++j) {
        float p = clampp(ps[j]);
        vfl += (-__logf(1.f - p)) * (0.75f * p * p);
      }
    }
    if (ts > 0.f) {
      const int lbl = gtl[b * NGT + mg];
      float p = clampp(row[lbl]);
      float l1 = __logf(1.f - p);
      vfl -= (-l1) * (0.75f * p * p);
      vfl += (-(ts * __logf(p) + (1.f - ts) * l1)) * ts;

      const float4 ab = reinterpret_cast<const float4*>(gtb)[b * NGT + mg];
      const float4 db = reinterpret_cast<const float4*>(dec)[idx];
      {
        float tlx = fmaxf(db.x, ab.x), tly = fmaxf(db.y, ab.y);
        float brx = fminf(db.z, ab.z), bry = fminf(db.w, ab.w);
        float iw = fmaxf(brx - tlx, 0.f), ih = fmaxf(bry - tly, 0.f);
        float inter = iw * ih;
        float ap = fmaxf(db.z - db.x, 0.f) * fmaxf(db.w - db.y, 0.f);
        float at = fmaxf(ab.z - ab.x, 0.f) * fmaxf(ab.w - ab.y, 0.f);
        float uni = ap + at - inter;
        float iou = inter / (uni + 1e-16f);
        float ctlx = fminf(db.x, ab.x), ctly = fminf(db.y, ab.y);
        float cbrx = fmaxf(db.z, ab.z), cbry = fmaxf(db.w, ab.w);
        float cw = fmaxf(cbrx - ctlx, 0.f), ch = fmaxf(cbry - ctly, 0.f);
        float ac = cw * ch;
        float gl = 1.f - (iou - (ac - uni) / (ac + 1e-16f));
        gi = gl * ts;
      }
      {
        const float4 pr = reinterpret_cast<const float4*>(priors)[n];
        const float s = pr.z;
        float dv[4] = {(pr.x - ab.x) / s, (pr.y - ab.y) / s,
                       (ab.z - pr.x) / s, (ab.w - pr.y) / s};
        const float* rrow = regp + idx * 32;
        float ce_sum = 0.f;
        #pragma unroll
        for (int side = 0; side < 4; ++side) {
          float tv = fminf(fmaxf(dv[side], 0.f), 6.9f);
          int tl_ = (int)tv;
          int tr_ = tl_ + 1; if (tr_ > 7) tr_ = 7;
          float wl = (float)(tl_ + 1) - tv;
          float wr = tv - (float)tl_;
          const float* lg = rrow + side * 8;
          float mx = lg[0];
          #pragma unroll
          for (int i = 1; i < 8; ++i) mx = fmaxf(mx, lg[i]);
          float se = 0.f;
          #pragma unroll
          for (int i = 0; i < 8; ++i) se += __expf(lg[i] - mx);
          float lse = __logf(se);
          float lp_tl = lg[tl_] - mx - lse;
          float lp_tr = lg[tr_] - mx - lse;
          ce_sum += -(lp_tl * wl + lp_tr * wr);
        }
        df = ce_sum * ts;
      }
    }
  }
  __shared__ float red[256];
  red[tid] = vfl; __syncthreads();
  for (int s = 128; s > 0; s >>= 1) { if (tid < s) red[tid] += red[tid + s]; __syncthreads(); }
  float vflb = red[0]; __syncthreads();
  red[tid] = gi; __syncthreads();
  for (int s = 128; s > 0; s >>= 1) { if (tid < s) red[tid] += red[tid + s]; __syncthreads(); }
  float gib = red[0]; __syncthreads();
  red[tid] = df; __syncthreads();
  for (int s = 128; s > 0; s >>= 1) { if (tid < s) red[tid] += red[tid + s]; __syncthreads(); }
  if (tid == 0) {
    int blk = blockIdx.y * gridDim.x + blockIdx.x;
    p_vfl[blk] = vflb;
    p_gi[blk] = gib;
    p_df[blk] = red[0];
  }
}

// ---------------- kernel 5: final reduction ----------------
__global__ __launch_bounds__(256) void k_final(
    const float* __restrict__ p_vfl, const float* __restrict__ p_gi,
    const float* __restrict__ p_df, const float* __restrict__ p_np,
    const float* __restrict__ p_ns, float* __restrict__ out, int nb)
{
  __shared__ double red[256];
  const float* arrs[5] = {p_vfl, p_gi, p_df, p_np, p_ns};
  double sums[5];
  for (int a = 0; a < 5; ++a) {
    double s = 0.0;
    for (int i = threadIdx.x; i < nb; i += 256) s += (double)arrs[a][i];
    red[threadIdx.x] = s; __syncthreads();
    for (int st = 128; st > 0; st >>= 1) {
      if (threadIdx.x < st) red[threadIdx.x] += red[threadIdx.x + st];
      __syncthreads();
    }
    sums[a] = red[0]; __syncthreads();
  }
  if (threadIdx.x == 0) {
    double npos = sums[3] > 1.0 ? sums[3] : 1.0;
    double ns = sums[4] > 1.0 ? sums[4] : 1.0;
    out[0] = (float)(sums[0] / npos + 2.0 * sums[1] / ns + 0.25 * sums[2] / ns);
  }
}

extern "C" void kernel_launch(void* const* d_in, const int* in_sizes, int n_in,
                              void* d_out, int out_size, void* d_ws, size_t ws_size,
                              hipStream_t stream) {
  const float* priors = (const float*)d_in[0];
  const float* dec    = (const float*)d_in[1];
  const float* clsp   = (const float*)d_in[2];
  const float* regp   = (const float*)d_in[3];
  const float* gtb    = (const float*)d_in[4];
  const int*   gtl    = (const int*)d_in[5];
  float* out = (float*)d_out;

  char* w = (char*)d_ws;
  size_t off = 0;
  auto take = [&](size_t bytes) -> char* {
    char* p = w + off;
    off += (bytes + 255) & ~(size_t)255;
    return p;
  };
  float* negsum        = (float*)take((size_t)BS * NP * 4);
  unsigned char* valid = (unsigned char*)take((size_t)BS * NP);
  u64* inboth          = (u64*)take((size_t)BS * NP * 16);
  u64* match           = (u64*)take((size_t)BS * NP * 16);
  float* tscore        = (float*)take((size_t)BS * NP * 4);
  int* mgt             = (int*)take((size_t)BS * NP * 4);
  const int NBX = (NP + 255) / 256;        // 34
  const int NBLK = NBX * BS;               // 1088
  float* p_vfl = (float*)take((size_t)NBLK * 4);
  float* p_gi  = (float*)take((size_t)NBLK * 4);
  float* p_df  = (float*)take((size_t)NBLK * 4);
  float* p_np  = (float*)take((size_t)NBLK * 4);
  float* p_ns  = (float*)take((size_t)NBLK * 4);
  const size_t ccost_bytes = (size_t)BS * NCLS * NP * 4;   // 87 MB
  const bool useT = (off + ccost_bytes + 256) <= ws_size;
  float* ccostT = useT ? (float*)take(ccost_bytes) : nullptr;

  hipMemsetAsync(match, 0, (size_t)BS * NP * 16, stream);

  dim3 gridA(NBX, BS);
  if (useT) {
    k_prep<true><<<gridA, 256, 0, stream>>>(priors, gtb, clsp, negsum, valid, inboth, ccostT);
    k_assign<true><<<dim3(BS * NGT / 4), 256, 0, stream>>>(dec, gtb, gtl, clsp, negsum,
                                                           valid, inboth, ccostT, match);
    k_post<true><<<gridA, 256, 0, stream>>>(dec, gtb, gtl, clsp, negsum, valid, inboth,
                                            ccostT, match, tscore, mgt, p_np, p_ns);
  } else {
    k_prep<false><<<gridA, 256, 0, stream>>>(priors, gtb, clsp, negsum, valid, inboth, nullptr);
    k_assign<false><<<dim3(BS * NGT / 4), 256, 0, stream>>>(dec, gtb, gtl, clsp, negsum,
                                                            valid, inboth, nullptr, match);
    k_post<false><<<gridA, 256, 0, stream>>>(dec, gtb, gtl, clsp, negsum, valid, inboth,
                                             nullptr, match, tscore, mgt, p_np, p_ns);
  }
  k_loss<<<gridA, 256, 0, stream>>>(priors, dec, clsp, regp, gtb, gtl,
                                    tscore, mgt, p_vfl, p_gi, p_df);
  k_final<<<1, 256, 0, stream>>>(p_vfl, p_gi, p_df, p_np, p_ns, out, NBLK);
}

// Round 4
// 501.222 us; speedup vs baseline: 2.0411x; 1.2622x over previous
//
#include <hip/hip_runtime.h>
#include <cstdint>
#include <cstddef>

#define NP    8500   // priors
#define BS    32     // batch
#define NGT   128    // gt boxes
#define NCLS  80     // classes
#define TOPKK 10

typedef unsigned long long u64;
typedef unsigned int u32;

static __device__ __forceinline__ float iou_prec(const float4 a, const float4 b) {
  float area_a = (a.z - a.x) * (a.w - a.y);
  float area_b = (b.z - b.x) * (b.w - b.y);
  float tlx = fmaxf(a.x, b.x), tly = fmaxf(a.y, b.y);
  float brx = fminf(a.z, b.z), bry = fminf(a.w, b.w);
  float ww = fmaxf(brx - tlx, 0.f), hh = fmaxf(bry - tly, 0.f);
  float inter = ww * hh;
  return inter / (area_a + area_b - inter + 1e-16f);
}

static __device__ __forceinline__ float iou_fast(const float4 a, const float4 b) {
  float area_a = (a.z - a.x) * (a.w - a.y);
  float area_b = (b.z - b.x) * (b.w - b.y);
  float tlx = fmaxf(a.x, b.x), tly = fmaxf(a.y, b.y);
  float brx = fminf(a.z, b.z), bry = fminf(a.w, b.w);
  float ww = fmaxf(brx - tlx, 0.f), hh = fmaxf(bry - tly, 0.f);
  float inter = ww * hh;
  return __fdividef(inter, area_a + area_b - inter + 1e-16f);
}

static __device__ __forceinline__ float clampp(float p) {
  return fminf(fmaxf(p, 1e-7f), 1.0f - 1e-7f);
}

// log((1-p)/p): one hw log
static __device__ __forceinline__ float wlog(float p) {
  return __logf((1.0f - p) / p);
}

static __device__ __forceinline__ u64 shflxor_u64(u64 v, int mask) {
  int lo = __shfl_xor((int)(u32)(v & 0xffffffffull), mask, 64);
  int hi = __shfl_xor((int)(u32)(v >> 32), mask, 64);
  return ((u64)(u32)hi << 32) | (u32)lo;
}

static __device__ __forceinline__ u32 f2u_mono(float f) {
  u32 b = __float_as_uint(f);
  return b ^ ((b & 0x80000000u) ? 0xffffffffu : 0x80000000u);
}

// ---------------- kernel 1: masks + negsum (+ transposed cls-cost rows) ----------------
template<bool TR>
__global__ __launch_bounds__(256) void k_prep(
    const float* __restrict__ priors, const float* __restrict__ gtb,
    const float* __restrict__ clsp,
    float* __restrict__ negsum, unsigned char* __restrict__ valid,
    u64* __restrict__ inboth, float* __restrict__ ccostT)
{
  __shared__ float4 sg[NGT];
  const int b = blockIdx.y;
  const int tid = threadIdx.x;
  if (tid < NGT) sg[tid] = reinterpret_cast<const float4*>(gtb + (size_t)b * NGT * 4)[tid];
  __syncthreads();
  const int n = blockIdx.x * 256 + tid;
  if (n >= NP) return;
  const float4 pr = reinterpret_cast<const float4*>(priors)[n];
  const float cx = pr.x, cy = pr.y, sw = pr.z, sh = pr.w;
  u64 m0 = 0, m1 = 0;
  bool anyv = false;
  const float CR = 2.5f;
  for (int g = 0; g < NGT; ++g) {
    float4 gb = sg[g];
    float ib = fminf(fminf(cx - gb.x, cy - gb.y), fminf(gb.z - cx, gb.w - cy));
    bool in_box = ib > 0.f;
    float gcx = (gb.x + gb.z) * 0.5f, gcy = (gb.y + gb.w) * 0.5f;
    float ic = fminf(fminf(cx - (gcx - CR * sw), cy - (gcy - CR * sh)),
                     fminf(gcx + CR * sw - cx, gcy + CR * sh - cy));
    bool in_ctr = ic > 0.f;
    anyv |= (in_box | in_ctr);
    if (in_box && in_ctr) {
      if (g < 64) m0 |= 1ull << g; else m1 |= 1ull << (g - 64);
    }
  }
  const size_t idx = (size_t)b * NP + n;
  valid[idx] = anyv ? 1 : 0;
  inboth[idx * 2] = m0;
  inboth[idx * 2 + 1] = m1;

  const float4* row4 = reinterpret_cast<const float4*>(clsp + idx * NCLS);
  float s = 0.f;
  #pragma unroll 5
  for (int i = 0; i < NCLS / 4; ++i) {
    float4 p4 = row4[i];
    float q0 = 1.f - clampp(p4.x), q1 = 1.f - clampp(p4.y);
    float q2 = 1.f - clampp(p4.z), q3 = 1.f - clampp(p4.w);
    s -= __logf((q0 * q1) * (q2 * q3));
  }
  negsum[idx] = s;

  if (TR) {
    #pragma unroll 5
    for (int i = 0; i < NCLS / 4; ++i) {
      float4 p4 = row4[i];   // L1 hit
      float w0 = wlog(clampp(p4.x)), w1 = wlog(clampp(p4.y));
      float w2 = wlog(clampp(p4.z)), w3 = wlog(clampp(p4.w));
      const size_t base = ((size_t)b * NCLS + i * 4) * NP + n;
      ccostT[base]          = s + w0;
      ccostT[base + NP]     = s + w1;
      ccostT[base + 2 * NP] = s + w2;
      ccostT[base + 3 * NP] = s + w3;
    }
  }
}

// ---------------- kernel 2: fused single-scan dyn_k + top-k selection ----------------
// All per-lane arrays use ONLY compile-time indices (rule #20: runtime indexing
// demotes to scratch; round-3 profile showed 537 MB scratch WRITE_SIZE).
template<bool TR>
__global__ __launch_bounds__(256) void k_assign(
    const float* __restrict__ dec, const float* __restrict__ gtb,
    const int* __restrict__ gtl, const float* __restrict__ clsp,
    const float* __restrict__ negsum, const unsigned char* __restrict__ valid,
    const u64* __restrict__ inboth, const float* __restrict__ ccostT,
    u64* __restrict__ match)
{
  const int bid = (int)((blockIdx.x & 7) * (gridDim.x >> 3) + (blockIdx.x >> 3));
  const int wid = (bid * 256 + (int)threadIdx.x) >> 6;
  const int lane = threadIdx.x & 63;
  const int b = wid >> 7;      // /NGT
  const int g = wid & 127;     // %NGT
  const float4 gb = reinterpret_cast<const float4*>(gtb)[b * NGT + g];
  const int l = gtl[b * NGT + g];
  const float4* decb = reinterpret_cast<const float4*>(dec) + (size_t)b * NP;
  const unsigned char* valb = valid + (size_t)b * NP;
  const u64* inbb = inboth + (size_t)b * NP * 2;
  const float* ccrow = TR ? (ccostT + ((size_t)b * NCLS + l) * NP) : nullptr;
  const float* negb = negsum + (size_t)b * NP;
  const float* clspb = clsp + (size_t)b * NP * NCLS;

  float t[TOPKK];          // ascending top-10 masked ious (t[9] = lane max)
  u64 k[TOPKK];            // ascending smallest-10 keys (k[0] = lane min)
  #pragma unroll
  for (int i = 0; i < TOPKK; ++i) { t[i] = 0.f; k[i] = ~0ull; }

  for (int n = lane; n < NP; n += 64) {
    const float4 db = decb[n];
    const bool vn = valb[n] != 0;
    const float iou = iou_fast(db, gb);
    const float v = vn ? iou : 0.f;
    if (v > t[0]) {
      t[0] = v;
      #pragma unroll
      for (int i = 0; i < TOPKK - 1; ++i) {
        if (t[i] > t[i + 1]) { float tmp = t[i]; t[i] = t[i + 1]; t[i + 1] = tmp; }
        else break;
      }
    }
    float base;
    if (TR) base = ccrow[n];
    else {
      float p = clampp(clspb[(size_t)n * NCLS + l]);
      base = negb[n] + wlog(p);
    }
    const bool inb = ((inbb[2 * (size_t)n + (g >> 6)] >> (g & 63)) & 1ull) != 0;
    float c = fmaf(-3.f, __logf(iou + 1e-8f), base);
    c += inb ? 0.f : 1e5f;
    c += vn ? 0.f : 1e8f;
    const u64 key = ((u64)f2u_mono(c) << 32) | (u32)n;
    if (key < k[TOPKK - 1]) {
      k[TOPKK - 1] = key;
      #pragma unroll
      for (int i = TOPKK - 1; i > 0; --i) {
        if (k[i] < k[i - 1]) { u64 tmp = k[i]; k[i] = k[i - 1]; k[i - 1] = tmp; }
        else break;
      }
    }
  }

  // ---- merge ious across lanes -> dyn_k (extract-and-shift, static idx) ----
  float sum = 0.f;
  #pragma unroll
  for (int r = 0; r < TOPKK; ++r) {
    float cand = t[TOPKK - 1];               // lane's current max (static)
    float m = cand;
    #pragma unroll
    for (int off = 32; off; off >>= 1) m = fmaxf(m, __shfl_xor(m, off, 64));
    sum += m;                                // masked ious are >= 0
    u64 ball = __ballot(cand == m);
    int win = __ffsll(ball) - 1;
    if (lane == win) {
      #pragma unroll
      for (int i = TOPKK - 1; i > 0; --i) t[i] = t[i - 1];
      t[0] = -1.f;
    }
  }
  int dynk = (int)sum;
  if (dynk < 1) dynk = 1;
  if (dynk > TOPKK) dynk = TOPKK;

  // ---- extract dyn_k smallest keys (extract-and-shift, static idx) ----
  for (int r = 0; r < dynk; ++r) {
    u64 cand = k[0];                          // lane's current min (static)
    u64 m = cand;
    #pragma unroll
    for (int off = 32; off; off >>= 1) {
      u64 o = shflxor_u64(m, off);
      if (o < m) m = o;
    }
    u64 ball = __ballot(cand == m);
    int win = __ffsll(ball) - 1;
    if (lane == win) {
      u32 nn = (u32)(m & 0xffffffffu);
      atomicOr(&match[((size_t)b * NP + nn) * 2 + (g >> 6)], 1ull << (g & 63));
      #pragma unroll
      for (int i = 0; i < TOPKK - 1; ++i) k[i] = k[i + 1];
      k[TOPKK - 1] = ~0ull;
    }
  }
}

// ---------------- kernel 3: resolve matches ----------------
template<bool TR>
__global__ __launch_bounds__(256) void k_post(
    const float* __restrict__ dec, const float* __restrict__ gtb,
    const int* __restrict__ gtl, const float* __restrict__ clsp,
    const float* __restrict__ negsum, const unsigned char* __restrict__ valid,
    const u64* __restrict__ inboth, const float* __restrict__ ccostT,
    const u64* __restrict__ match,
    float* __restrict__ tscore, int* __restrict__ mgt,
    float* __restrict__ p_np, float* __restrict__ p_ns)
{
  const int b = blockIdx.y;
  const int tid = threadIdx.x;
  const int n = blockIdx.x * 256 + tid;
  float ts = 0.f, fgf = 0.f;
  if (n < NP) {
    const size_t idx = (size_t)b * NP + n;
    u64 m0 = match[idx * 2], m1 = match[idx * 2 + 1];
    int pop = __popcll(m0) + __popcll(m1);
    int mg = 0;
    if (pop > 0) {
      fgf = 1.f;
      float4 db = reinterpret_cast<const float4*>(dec)[idx];
      int g;
      if (pop == 1) {
        g = m0 ? (__ffsll(m0) - 1) : (64 + __ffsll(m1) - 1);
      } else {
        bool vn = valid[idx] != 0;
        u64 ib0 = inboth[idx * 2], ib1 = inboth[idx * 2 + 1];
        float nsv = negsum[idx];
        float bc = 3.4e38f; int bg_ = 0;
        for (int gg = 0; gg < NGT; ++gg) {
          float4 gbv = reinterpret_cast<const float4*>(gtb)[b * NGT + gg];
          int lg_ = gtl[b * NGT + gg];
          float base;
          if (TR) base = ccostT[((size_t)b * NCLS + lg_) * NP + n];
          else    base = nsv + wlog(clampp(clsp[idx * NCLS + lg_]));
          bool inb = (((gg < 64) ? (ib0 >> gg) : (ib1 >> (gg - 64))) & 1ull) != 0;
          float iou = iou_fast(db, gbv);
          float c = fmaf(-3.f, __logf(iou + 1e-8f), base);
          c += inb ? 0.f : 1e5f;
          c += vn ? 0.f : 1e8f;
          if (c < bc) { bc = c; bg_ = gg; }
        }
        g = bg_;
      }
      mg = g;
      ts = iou_prec(db, reinterpret_cast<const float4*>(gtb)[b * NGT + g]);
    }
    tscore[idx] = ts;
    mgt[idx] = mg;
  }
  __shared__ float red[256];
  red[tid] = fgf; __syncthreads();
  for (int s = 128; s > 0; s >>= 1) { if (tid < s) red[tid] += red[tid + s]; __syncthreads(); }
  float npb = red[0]; __syncthreads();
  red[tid] = ts; __syncthreads();
  for (int s = 128; s > 0; s >>= 1) { if (tid < s) red[tid] += red[tid + s]; __syncthreads(); }
  if (tid == 0) {
    int blk = blockIdx.y * gridDim.x + blockIdx.x;
    p_np[blk] = npb;
    p_ns[blk] = red[0];
  }
}

// ---------------- kernel 4: VFL + GIoU + DFL partials ----------------
__global__ __launch_bounds__(256) void k_loss(
    const float* __restrict__ priors, const float* __restrict__ dec,
    const float* __restrict__ clsp, const float* __restrict__ regp,
    const float* __restrict__ gtb, const int* __restrict__ gtl,
    const float* __restrict__ tscore, const int* __restrict__ mgt,
    float* __restrict__ p_vfl, float* __restrict__ p_gi, float* __restrict__ p_df)
{
  const int b = blockIdx.y;
  const int tid = threadIdx.x;
  const int n = blockIdx.x * 256 + tid;
  float vfl = 0.f, gi = 0.f, df = 0.f;
  if (n < NP) {
    const size_t idx = (size_t)b * NP + n;
    const float ts = tscore[idx];
    const int mg = mgt[idx];
    const float* row = clsp + idx * NCLS;
    const float4* row4 = reinterpret_cast<const float4*>(row);
    #pragma unroll 5
    for (int i = 0; i < NCLS / 4; ++i) {
      float4 p4 = row4[i];
      float ps[4] = {p4.x, p4.y, p4.z, p4.w};
      #pragma unroll
      for (int j = 0; j < 4; ++j) {
        float p = clampp(ps[j]);
        vfl += (-__logf(1.f - p)) * (0.75f * p * p);
      }
    }
    if (ts > 0.f) {
      const int lbl = gtl[b * NGT + mg];
      float p = clampp(row[lbl]);
      float l1 = __logf(1.f - p);
      vfl -= (-l1) * (0.75f * p * p);
      vfl += (-(ts * __logf(p) + (1.f - ts) * l1)) * ts;

      const float4 ab = reinterpret_cast<const float4*>(gtb)[b * NGT + mg];
      const float4 db = reinterpret_cast<const float4*>(dec)[idx];
      {
        float tlx = fmaxf(db.x, ab.x), tly = fmaxf(db.y, ab.y);
        float brx = fminf(db.z, ab.z), bry = fminf(db.w, ab.w);
        float iw = fmaxf(brx - tlx, 0.f), ih = fmaxf(bry - tly, 0.f);
        float inter = iw * ih;
        float ap = fmaxf(db.z - db.x, 0.f) * fmaxf(db.w - db.y, 0.f);
        float at = fmaxf(ab.z - ab.x, 0.f) * fmaxf(ab.w - ab.y, 0.f);
        float uni = ap + at - inter;
        float iou = inter / (uni + 1e-16f);
        float ctlx = fminf(db.x, ab.x), ctly = fminf(db.y, ab.y);
        float cbrx = fmaxf(db.z, ab.z), cbry = fmaxf(db.w, ab.w);
        float cw = fmaxf(cbrx - ctlx, 0.f), ch = fmaxf(cbry - ctly, 0.f);
        float ac = cw * ch;
        float gl = 1.f - (iou - (ac - uni) / (ac + 1e-16f));
        gi = gl * ts;
      }
      {
        const float4 pr = reinterpret_cast<const float4*>(priors)[n];
        const float s = pr.z;
        float dv[4] = {(pr.x - ab.x) / s, (pr.y - ab.y) / s,
                       (ab.z - pr.x) / s, (ab.w - pr.y) / s};
        const float* rrow = regp + idx * 32;
        float ce_sum = 0.f;
        #pragma unroll
        for (int side = 0; side < 4; ++side) {
          float tv = fminf(fmaxf(dv[side], 0.f), 6.9f);
          int tl_ = (int)tv;
          int tr_ = tl_ + 1; if (tr_ > 7) tr_ = 7;
          float wl = (float)(tl_ + 1) - tv;
          float wr = tv - (float)tl_;
          const float* lg = rrow + side * 8;
          float mx = lg[0];
          #pragma unroll
          for (int i = 1; i < 8; ++i) mx = fmaxf(mx, lg[i]);
          float se = 0.f;
          #pragma unroll
          for (int i = 0; i < 8; ++i) se += __expf(lg[i] - mx);
          float lse = __logf(se);
          float lp_tl = lg[tl_] - mx - lse;
          float lp_tr = lg[tr_] - mx - lse;
          ce_sum += -(lp_tl * wl + lp_tr * wr);
        }
        df = ce_sum * ts;
      }
    }
  }
  __shared__ float red[256];
  red[tid] = vfl; __syncthreads();
  for (int s = 128; s > 0; s >>= 1) { if (tid < s) red[tid] += red[tid + s]; __syncthreads(); }
  float vflb = red[0]; __syncthreads();
  red[tid] = gi; __syncthreads();
  for (int s = 128; s > 0; s >>= 1) { if (tid < s) red[tid] += red[tid + s]; __syncthreads(); }
  float gib = red[0]; __syncthreads();
  red[tid] = df; __syncthreads();
  for (int s = 128; s > 0; s >>= 1) { if (tid < s) red[tid] += red[tid + s]; __syncthreads(); }
  if (tid == 0) {
    int blk = blockIdx.y * gridDim.x + blockIdx.x;
    p_vfl[blk] = vflb;
    p_gi[blk] = gib;
    p_df[blk] = red[0];
  }
}

// ---------------- kernel 5: final reduction ----------------
__global__ __launch_bounds__(256) void k_final(
    const float* __restrict__ p_vfl, const float* __restrict__ p_gi,
    const float* __restrict__ p_df, const float* __restrict__ p_np,
    const float* __restrict__ p_ns, float* __restrict__ out, int nb)
{
  __shared__ double red[256];
  const float* arrs[5] = {p_vfl, p_gi, p_df, p_np, p_ns};
  double sums[5];
  for (int a = 0; a < 5; ++a) {
    double s = 0.0;
    for (int i = threadIdx.x; i < nb; i += 256) s += (double)arrs[a][i];
    red[threadIdx.x] = s; __syncthreads();
    for (int st = 128; st > 0; st >>= 1) {
      if (threadIdx.x < st) red[threadIdx.x] += red[threadIdx.x + st];
      __syncthreads();
    }
    sums[a] = red[0]; __syncthreads();
  }
  if (threadIdx.x == 0) {
    double npos = sums[3] > 1.0 ? sums[3] : 1.0;
    double ns = sums[4] > 1.0 ? sums[4] : 1.0;
    out[0] = (float)(sums[0] / npos + 2.0 * sums[1] / ns + 0.25 * sums[2] / ns);
  }
}

extern "C" void kernel_launch(void* const* d_in, const int* in_sizes, int n_in,
                              void* d_out, int out_size, void* d_ws, size_t ws_size,
                              hipStream_t stream) {
  const float* priors = (const float*)d_in[0];
  const float* dec    = (const float*)d_in[1];
  const float* clsp   = (const float*)d_in[2];
  const float* regp   = (const float*)d_in[3];
  const float* gtb    = (const float*)d_in[4];
  const int*   gtl    = (const int*)d_in[5];
  float* out = (float*)d_out;

  char* w = (char*)d_ws;
  size_t off = 0;
  auto take = [&](size_t bytes) -> char* {
    char* p = w + off;
    off += (bytes + 255) & ~(size_t)255;
    return p;
  };
  float* negsum        = (float*)take((size_t)BS * NP * 4);
  unsigned char* valid = (unsigned char*)take((size_t)BS * NP);
  u64* inboth          = (u64*)take((size_t)BS * NP * 16);
  u64* match           = (u64*)take((size_t)BS * NP * 16);
  float* tscore        = (float*)take((size_t)BS * NP * 4);
  int* mgt             = (int*)take((size_t)BS * NP * 4);
  const int NBX = (NP + 255) / 256;        // 34
  const int NBLK = NBX * BS;               // 1088
  float* p_vfl = (float*)take((size_t)NBLK * 4);
  float* p_gi  = (float*)take((size_t)NBLK * 4);
  float* p_df  = (float*)take((size_t)NBLK * 4);
  float* p_np  = (float*)take((size_t)NBLK * 4);
  float* p_ns  = (float*)take((size_t)NBLK * 4);
  const size_t ccost_bytes = (size_t)BS * NCLS * NP * 4;   // 87 MB
  const bool useT = (off + ccost_bytes + 256) <= ws_size;
  float* ccostT = useT ? (float*)take(ccost_bytes) : nullptr;

  hipMemsetAsync(match, 0, (size_t)BS * NP * 16, stream);

  dim3 gridA(NBX, BS);
  if (useT) {
    k_prep<true><<<gridA, 256, 0, stream>>>(priors, gtb, clsp, negsum, valid, inboth, ccostT);
    k_assign<true><<<dim3(BS * NGT / 4), 256, 0, stream>>>(dec, gtb, gtl, clsp, negsum,
                                                           valid, inboth, ccostT, match);
    k_post<true><<<gridA, 256, 0, stream>>>(dec, gtb, gtl, clsp, negsum, valid, inboth,
                                            ccostT, match, tscore, mgt, p_np, p_ns);
  } else {
    k_prep<false><<<gridA, 256, 0, stream>>>(priors, gtb, clsp, negsum, valid, inboth, nullptr);
    k_assign<false><<<dim3(BS * NGT / 4), 256, 0, stream>>>(dec, gtb, gtl, clsp, negsum,
                                                            valid, inboth, nullptr, match);
    k_post<false><<<gridA, 256, 0, stream>>>(dec, gtb, gtl, clsp, negsum, valid, inboth,
                                             nullptr, match, tscore, mgt, p_np, p_ns);
  }
  k_loss<<<gridA, 256, 0, stream>>>(priors, dec, clsp, regp, gtb, gtl,
                                    tscore, mgt, p_vfl, p_gi, p_df);
  k_final<<<1, 256, 0, stream>>>(p_vfl, p_gi, p_df, p_np, p_ns, out, NBLK);
}